// Round 1
// baseline (1290.761 us; speedup 1.0000x reference)
//
#include <hip/hip_runtime.h>

#define NN 384      // items
#define MM 128      // targets
#define TT 768      // threads (12 waves, single workgroup)
#define NITERS 100
#define KBUD 40.0f
#define LR_C 0.1f
#define MOM_C 0.9f

__device__ __forceinline__ unsigned sortable_bits(float f) {
    unsigned u = __float_as_uint(f);
    return (u & 0x80000000u) ? ~u : (u | 0x80000000u);
}

__global__ __launch_bounds__(TT) void submod_kernel(
    const float* __restrict__ Y,    // [NN][MM] row-major
    const float* __restrict__ Z0,   // [NN]
    float* __restrict__ out,        // [NN]
    float* __restrict__ YT,         // ws: [MM][NN]
    int useT)
{
    __shared__ __align__(16) float Zbuf[2][NN];
    __shared__ __align__(16) float Wv[NN];      // Znew, then W = Znew + LR*g
    __shared__ float Pcol[MM];
    __shared__ float partP[6][MM];
    __shared__ float partG[2][NN];
    __shared__ float Abp[2*NN];                 // 768 breakpoints
    __shared__ float Hbp[2*NN];                 // h at each breakpoint
    __shared__ float sAlpha;

    const int tid = threadIdx.x;

    // one-time transpose Y -> YT (global scratch), for coalesced phase G
    if (useT) {
        for (int idx = tid; idx < NN*MM; idx += TT) {
            int i = idx >> 7, j = idx & (MM-1);
            YT[j*NN + i] = Y[idx];
        }
    }
    for (int i = tid; i < NN; i += TT) {
        float z = Z0[i];
        Zbuf[0][i] = z;
        Zbuf[1][i] = z;
    }
    __threadfence_block();
    __syncthreads();

    int s = 0;  // Z = Zbuf[s], Zprev = Zbuf[s^1]
    for (int it = 0; it < NITERS; ++it) {
        // ---- momentum extrapolation: Wv = Znew = Z + MOM*(Z - Zprev)
        for (int i = tid; i < NN; i += TT) {
            float z = Zbuf[s][i], zp = Zbuf[s^1][i];
            Wv[i] = fmaf(MOM_C, z - zp, z);
        }
        __syncthreads();

        // ---- phase P: column products P_j = prod_i (1 - y_ij * Znew_i)
        {
            int c = tid & (MM-1);
            int chunk = tid >> 7;          // 0..5, 64 rows each
            int i0 = chunk * 64;
            const float* yp = Y + i0*MM + c;
            float p = 1.0f;
            #pragma unroll 8
            for (int r = 0; r < 64; ++r) {
                float y = yp[r*MM];        // coalesced: lanes span c
                float z = Wv[i0 + r];      // LDS broadcast
                p *= fmaf(-y, z, 1.0f);
            }
            partP[chunk][c] = p;
        }
        __syncthreads();
        if (tid < MM) {
            float p01 = partP[0][tid] * partP[1][tid];
            float p23 = partP[2][tid] * partP[3][tid];
            float p45 = partP[4][tid] * partP[5][tid];
            Pcol[tid] = p01 * p23 * p45;
        }
        __syncthreads();

        // ---- phase G: g_i = sum_j y_ij * P_j / t_ij
        {
            int jh = (tid >= NN) ? 1 : 0;
            int i  = tid - jh*NN;
            int j0 = jh * 64;
            float zi = Wv[i];
            float acc = 0.0f;
            #pragma unroll 4
            for (int q = 0; q < 64; ++q) {
                int j = j0 + q;
                float y = useT ? YT[j*NN + i]     // coalesced: lanes span i
                               : Y[i*MM + j];     // fallback (strided)
                float t = fmaf(-y, zi, 1.0f);
                float r0 = __builtin_amdgcn_rcpf(t);
                float e  = fmaf(-t, r0, 2.0f);    // Newton: r = r0*(2 - t*r0)
                float rr = r0 * e;
                float cb = y * Pcol[j] * rr;
                cb = (t == 0.0f) ? 0.0f : cb;     // freak exact-zero guard
                acc += cb;
            }
            partG[jh][i] = acc;
        }
        __syncthreads();

        // ---- W = Znew + LR*g  (ascent: project(Znew - LR*grad_neg)); breakpoints
        for (int i = tid; i < NN; i += TT) {
            float g = partG[0][i] + partG[1][i];
            float w = fmaf(LR_C, g, Wv[i]);
            Wv[i] = w;
            Abp[i]      = w - 1.0f;   // (Z*c-1)/c^2 with c=1
            Abp[NN + i] = w;          // Z/c
        }
        __syncthreads();

        // ---- phase H: h(a_p) = sum_i clip(W_i - a_p, 0, 1) for all 768 breakpoints
        {
            float a = Abp[tid];
            float h0 = 0.f, h1 = 0.f, h2 = 0.f, h3 = 0.f;
            const float4* w4 = (const float4*)Wv;
            #pragma unroll 8
            for (int q = 0; q < NN/4; ++q) {
                float4 w = w4[q];              // LDS broadcast b128
                h0 += fminf(fmaxf(w.x - a, 0.f), 1.f);
                h1 += fminf(fmaxf(w.y - a, 0.f), 1.f);
                h2 += fminf(fmaxf(w.z - a, 0.f), 1.f);
                h3 += fminf(fmaxf(w.w - a, 0.f), 1.f);
            }
            Hbp[tid] = (h0 + h1) + (h2 + h3);
        }
        __syncthreads();

        // ---- wave-0 reductions: find idx / a_lo / a_hi / hprev per reference rules
        if (tid < 64) {
            unsigned long long mCond = ~0ull, mAll = ~0ull;
            #pragma unroll
            for (int c2 = 0; c2 < 12; ++c2) {
                int p = c2*64 + tid;
                float a = Abp[p], h = Hbp[p];
                unsigned long long pk =
                    ((unsigned long long)sortable_bits(a) << 32) | (unsigned)p;
                if (h < KBUD && pk < mCond) mCond = pk;   // min breakpoint with h<k
                if (pk < mAll) mAll = pk;                 // global min
            }
            #pragma unroll
            for (int d = 1; d < 64; d <<= 1) {
                unsigned long long o1 = __shfl_xor(mCond, d);
                unsigned long long o2 = __shfl_xor(mAll, d);
                if (o1 < mCond) mCond = o1;
                if (o2 < mAll)  mAll  = o2;
            }
            int   pHi = (int)(mCond & 0xffffffffu);
            float aHi = Abp[pHi];
            float hHi = Hbp[pHi];

            int r = 0;
            unsigned long long mLo = 0ull, m2 = ~0ull;
            #pragma unroll
            for (int c2 = 0; c2 < 12; ++c2) {
                int p = c2*64 + tid;
                float a = Abp[p];
                unsigned long long pk =
                    ((unsigned long long)sortable_bits(a) << 32) | (unsigned)p;
                if (a < aHi) { r++; if (pk > mLo) mLo = pk; }   // max below aHi
                if (pk > mAll && pk < m2) m2 = pk;              // 2nd-smallest
            }
            #pragma unroll
            for (int d = 1; d < 64; d <<= 1) {
                r += __shfl_xor(r, d);
                unsigned long long o1 = __shfl_xor(mLo, d);
                unsigned long long o2 = __shfl_xor(m2, d);
                if (o1 > mLo) mLo = o1;
                if (o2 < m2)  m2  = o2;
            }
            if (tid == 0) {
                float aLo, hprev, aHiE = aHi, hHiE = hHi;
                if (r >= 2) {            // normal case (always, for n >> k)
                    int pLo = (int)(mLo & 0xffffffffu);
                    aLo = Abp[pLo]; hprev = Hbp[pLo];
                } else if (r == 1) {     // idx==1 quirk: hprev = n
                    int pLo = (int)(mLo & 0xffffffffu);
                    aLo = Abp[pLo]; hprev = (float)NN;
                } else {                 // idx forced from 0 to 1
                    int p1 = (int)(mAll & 0xffffffffu);
                    int p2 = (int)(m2  & 0xffffffffu);
                    aLo = Abp[p1]; aHiE = Abp[p2]; hHiE = Hbp[p2];
                    hprev = (float)NN;
                }
                sAlpha = aLo + (aHiE - aLo) * (hprev - KBUD) / (hprev - hHiE);
            }
        }
        __syncthreads();

        // ---- Z_next = clip(W - alpha*, 0, 1); carry (Z_next, Z)
        for (int i = tid; i < NN; i += TT) {
            float zn = Wv[i] - sAlpha;
            zn = fminf(fmaxf(zn, 0.0f), 1.0f);
            Zbuf[s^1][i] = zn;
        }
        s ^= 1;
        __syncthreads();
    }

    for (int i = tid; i < NN; i += TT) out[i] = Zbuf[s][i];
}

extern "C" void kernel_launch(void* const* d_in, const int* in_sizes, int n_in,
                              void* d_out, int out_size, void* d_ws, size_t ws_size,
                              hipStream_t stream) {
    const float* Y  = (const float*)d_in[0];   // Yhat [384*128]
    const float* Z0 = (const float*)d_in[1];   // Z_init [384]
    float* out = (float*)d_out;
    float* YT  = (float*)d_ws;
    int useT = (ws_size >= (size_t)(NN * MM * sizeof(float))) ? 1 : 0;
    submod_kernel<<<1, TT, 0, stream>>>(Y, Z0, out, YT, useT);
}

// Round 3
// 1041.149 us; speedup vs baseline: 1.2397x; 1.2397x over previous
//
#include <hip/hip_runtime.h>

#define NN 384
#define MM 128
#define TT 768
#define NITERS 100
#define KBUD 40.0f
#define LR_C 0.1f
#define MOM_C 0.9f

__device__ __forceinline__ unsigned sortable_bits(float f) {
    unsigned u = __float_as_uint(f);
    return (u & 0x80000000u) ? ~u : (u | 0x80000000u);
}

__device__ __forceinline__ float rcp_nr(float t) {
    // signed reciprocal, 1 Newton step (matches R1's bit-exact run)
    float r0 = __builtin_amdgcn_rcpf(t);
    return r0 * fmaf(-t, r0, 2.0f);
}

__global__ __launch_bounds__(TT, 3) void submod_kernel(
    const float* __restrict__ Y,    // [NN][MM] row-major
    const float* __restrict__ Z0,   // [NN]
    float* __restrict__ out)        // [NN]
{
    __shared__ __align__(16) float Zb[NN];        // current Z
    __shared__ __align__(16) float Wv[NN];        // Znew, then W = Znew + LR*g
    __shared__ __align__(16) float Pcol[MM];
    __shared__ __align__(16) float partP[6][MM];
    __shared__ __align__(16) float partG[2][NN];
    __shared__ __align__(16) float partH[2*NN][4]; // [bp][quarter]
    __shared__ __align__(16) float Hbp[2*NN];
    __shared__ float sAlpha;

    const int tid = threadIdx.x;

    // ---------- one-time: cache Y in registers, two layouts ----------
    const int c     = tid & (MM - 1);   // phase-P column
    const int chunk = tid >> 7;         // 0..5  (64-row chunk)
    const int i0    = chunk * 64;
    float yP[64];
    #pragma unroll
    for (int r = 0; r < 64; ++r) yP[r] = Y[(i0 + r) * MM + c];

    const int jh = (tid >= NN) ? 1 : 0; // phase-G j-half
    const int gi = tid - jh * NN;       // 0..383 row
    const int j0 = jh * 64;
    float yG[64];
    {
        const float4* yrow = (const float4*)(Y + gi * MM + j0);
        #pragma unroll
        for (int q = 0; q < 16; ++q) {
            float4 v = yrow[q];
            yG[4*q+0] = v.x; yG[4*q+1] = v.y; yG[4*q+2] = v.z; yG[4*q+3] = v.w;
        }
    }

    if (tid < NN) {
        float z = Z0[tid];
        Zb[tid] = z;
        Wv[tid] = z;                    // first Znew = Z0 (Z == Zprev)
    }
    __syncthreads();

    const int bpg = tid >> 2;           // 0..191: breakpoint group (4 bps)
    const int qh  = tid & 3;            // W quarter handled by this thread

    for (int it = 0; it < NITERS; ++it) {
        // ---- phase P: partial column products over this thread's 64 rows ----
        {
            float p0 = 1.f, p1 = 1.f, p2 = 1.f, p3 = 1.f;
            const float4* W4 = (const float4*)(Wv + i0);
            #pragma unroll
            for (int r = 0; r < 16; ++r) {
                float4 z4 = W4[r];
                p0 *= fmaf(-yP[4*r+0], z4.x, 1.f);
                p1 *= fmaf(-yP[4*r+1], z4.y, 1.f);
                p2 *= fmaf(-yP[4*r+2], z4.z, 1.f);
                p3 *= fmaf(-yP[4*r+3], z4.w, 1.f);
            }
            partP[chunk][c] = (p0 * p1) * (p2 * p3);
        }
        __syncthreads();
        if (tid < MM) {
            Pcol[tid] = ((partP[0][tid] * partP[1][tid]) *
                         (partP[2][tid] * partP[3][tid])) *
                        (partP[4][tid] * partP[5][tid]);
        }
        __syncthreads();

        // ---- phase G: g_i partial over this thread's 64 j's (registers) ----
        // NOTE: t = 1 - y*zi is legitimately NEGATIVE when momentum pushes
        // Znew past 1 — must use signed reciprocal (no clamp!). t==0 exact
        // implies P_j==0; zero that term like R1 did.
        {
            float zi = Wv[gi];
            float a0 = 0.f, a1 = 0.f;
            const float4* P4 = (const float4*)(Pcol + j0);
            #pragma unroll
            for (int q = 0; q < 16; ++q) {
                float4 pv = P4[q];
                float y0 = yG[4*q+0], t0 = fmaf(-y0, zi, 1.f);
                float c0 = y0 * pv.x * rcp_nr(t0);
                a0 += (t0 == 0.0f) ? 0.0f : c0;
                float y1 = yG[4*q+1], t1 = fmaf(-y1, zi, 1.f);
                float c1 = y1 * pv.y * rcp_nr(t1);
                a1 += (t1 == 0.0f) ? 0.0f : c1;
                float y2 = yG[4*q+2], t2 = fmaf(-y2, zi, 1.f);
                float c2 = y2 * pv.z * rcp_nr(t2);
                a0 += (t2 == 0.0f) ? 0.0f : c2;
                float y3 = yG[4*q+3], t3 = fmaf(-y3, zi, 1.f);
                float c3 = y3 * pv.w * rcp_nr(t3);
                a1 += (t3 == 0.0f) ? 0.0f : c3;
            }
            partG[jh][gi] = a0 + a1;
        }
        __syncthreads();

        // ---- W = Znew + LR*g ----
        if (tid < NN) {
            float g = partG[0][tid] + partG[1][tid];
            Wv[tid] = fmaf(LR_C, g, Wv[tid]);
        }
        __syncthreads();

        // ---- phase H: h at 4 bps over one W-quarter per thread ----
        {
            const int pb  = bpg * 4;                  // first bp of group
            const int wb  = (pb < NN) ? pb : pb - NN; // W index
            const float sub = (pb < NN) ? 1.0f : 0.0f;
            float4 av = *(const float4*)(Wv + wb);
            const float A0 = av.x - sub, A1 = av.y - sub;
            const float A2 = av.z - sub, A3 = av.w - sub;
            float h0 = 0.f, h1 = 0.f, h2 = 0.f, h3 = 0.f;
            const float4* W4 = (const float4*)(Wv + qh * 96);
            #pragma unroll
            for (int s = 0; s < 24; ++s) {
                float4 w = W4[s];
                h0 += __builtin_amdgcn_fmed3f(w.x - A0, 0.f, 1.f)
                    + __builtin_amdgcn_fmed3f(w.y - A0, 0.f, 1.f)
                    + __builtin_amdgcn_fmed3f(w.z - A0, 0.f, 1.f)
                    + __builtin_amdgcn_fmed3f(w.w - A0, 0.f, 1.f);
                h1 += __builtin_amdgcn_fmed3f(w.x - A1, 0.f, 1.f)
                    + __builtin_amdgcn_fmed3f(w.y - A1, 0.f, 1.f)
                    + __builtin_amdgcn_fmed3f(w.z - A1, 0.f, 1.f)
                    + __builtin_amdgcn_fmed3f(w.w - A1, 0.f, 1.f);
                h2 += __builtin_amdgcn_fmed3f(w.x - A2, 0.f, 1.f)
                    + __builtin_amdgcn_fmed3f(w.y - A2, 0.f, 1.f)
                    + __builtin_amdgcn_fmed3f(w.z - A2, 0.f, 1.f)
                    + __builtin_amdgcn_fmed3f(w.w - A2, 0.f, 1.f);
                h3 += __builtin_amdgcn_fmed3f(w.x - A3, 0.f, 1.f)
                    + __builtin_amdgcn_fmed3f(w.y - A3, 0.f, 1.f)
                    + __builtin_amdgcn_fmed3f(w.z - A3, 0.f, 1.f)
                    + __builtin_amdgcn_fmed3f(w.w - A3, 0.f, 1.f);
            }
            partH[pb + 0][qh] = h0;
            partH[pb + 1][qh] = h1;
            partH[pb + 2][qh] = h2;
            partH[pb + 3][qh] = h3;
        }
        __syncthreads();

        // ---- combine H quarters (one b128 per bp, conflict-free) ----
        {
            float4 v = *(const float4*)(&partH[tid][0]);
            Hbp[tid] = (v.x + v.y) + (v.z + v.w);
        }
        __syncthreads();

        // ---- wave-0 reduce: a_hi = min bp with h<k; a_lo = max bp < a_hi ----
        if (tid < 64) {
            unsigned long long mCond = ~0ull;
            #pragma unroll
            for (int c2 = 0; c2 < 12; ++c2) {
                int p = c2 * 64 + tid;
                float a = (p < NN) ? (Wv[p] - 1.0f) : Wv[p - NN];
                float h = Hbp[p];
                unsigned long long pk =
                    ((unsigned long long)sortable_bits(a) << 32) | (unsigned)p;
                if (h < KBUD && pk < mCond) mCond = pk;
            }
            #pragma unroll
            for (int d = 1; d < 64; d <<= 1) {
                unsigned long long o = __shfl_xor(mCond, d);
                if (o < mCond) mCond = o;
            }
            int pHi = (int)(mCond & 0xffffffffu);
            float aHi = (pHi < NN) ? (Wv[pHi] - 1.0f) : Wv[pHi - NN];
            float hHi = Hbp[pHi];

            unsigned long long mLo = 0ull;
            #pragma unroll
            for (int c2 = 0; c2 < 12; ++c2) {
                int p = c2 * 64 + tid;
                float a = (p < NN) ? (Wv[p] - 1.0f) : Wv[p - NN];
                unsigned long long pk =
                    ((unsigned long long)sortable_bits(a) << 32) | (unsigned)p;
                if (a < aHi && pk > mLo) mLo = pk;
            }
            #pragma unroll
            for (int d = 1; d < 64; d <<= 1) {
                unsigned long long o = __shfl_xor(mLo, d);
                if (o > mLo) mLo = o;
            }
            if (tid == 0) {
                int pLo = (int)(mLo & 0xffffffffu);
                float aLo = (pLo < NN) ? (Wv[pLo] - 1.0f) : Wv[pLo - NN];
                float hLo = Hbp[pLo];
                sAlpha = aLo + (aHi - aLo) * (hLo - KBUD) / (hLo - hHi);
            }
        }
        __syncthreads();

        // ---- fused update + momentum: Z = clip(W-a); Wv = Z + MOM*(Z - Zold) ----
        if (tid < NN) {
            float w  = Wv[tid];
            float zn = __builtin_amdgcn_fmed3f(w - sAlpha, 0.f, 1.f);
            float zc = Zb[tid];
            Zb[tid] = zn;
            Wv[tid] = fmaf(MOM_C, zn - zc, zn);
        }
        __syncthreads();
    }

    if (tid < NN) out[tid] = Zb[tid];
}

extern "C" void kernel_launch(void* const* d_in, const int* in_sizes, int n_in,
                              void* d_out, int out_size, void* d_ws, size_t ws_size,
                              hipStream_t stream) {
    const float* Y  = (const float*)d_in[0];   // Yhat [384*128]
    const float* Z0 = (const float*)d_in[1];   // Z_init [384]
    float* out = (float*)d_out;
    (void)d_ws; (void)ws_size;
    submod_kernel<<<1, TT, 0, stream>>>(Y, Z0, out);
}